// Round 13
// baseline (176.949 us; speedup 1.0000x reference)
//
#include <hip/hip_runtime.h>

// Modulated deformable conv, fp32 in/out. B=4, CIN=COUT=256, H=W=64, KS=3, PAD=1.
// R13: k_all in 256-thr blocks (4 barrier domains/CU, grid 512, M=32, wave=64 couts);
// k_pre transpose vectorized (float4 loads, LDS transpose, 16B stores, 1024 blocks).
// ws: [xpairT 16 MB][wfrag 1.33 MB]; fp32 fallback if ws too small.

#define WOFF_FRAG_OFF 589824
typedef unsigned short ushort_t;
typedef unsigned int   uint_t;

using short8 = __attribute__((ext_vector_type(8))) short;
using f32x4  = __attribute__((ext_vector_type(4))) float;

struct __attribute__((packed, aligned(4))) pairf { float x, y; };

__device__ inline ushort_t f2bf(float v) {
    unsigned u = __float_as_uint(v);
    unsigned r = u + 0x7fffu + ((u >> 16) & 1u);   // RNE (inputs finite)
    return (ushort_t)(r >> 16);
}
__device__ inline float bflo(uint_t u) { return __uint_as_float(u << 16); }
__device__ inline float bfhi(uint_t u) { return __uint_as_float(u & 0xffff0000u); }

// k_pre: blocks [0,XB): xpairT transpose (16 idx x 256 cin per block);
// [XB,XB+288): w_conv frags; [XB+288,XB+324): w_off frags.
__global__ __launch_bounds__(256) void k_pre(
    const float* __restrict__ x,
    const float* __restrict__ w_conv,
    const float* __restrict__ w_off,
    ushort_t* __restrict__ wfrag,
    uint_t* __restrict__ xpair,
    int XB)
{
    __shared__ uint_t tl[16 * 256];                  // 16 KB
    const int bid = blockIdx.x;
    const int t = threadIdx.x;
    if (bid < XB) {
        const int b    = bid >> 8;                   // 256 blocks per batch
        const int idx0 = (bid & 255) << 4;           // 16 idx rows
        const float* xp = x + (b << 20) + (t << 12) + idx0;
        float v[17];
#pragma unroll
        for (int g = 0; g < 4; ++g) {
            const float4 f = *(const float4*)(xp + g * 4);
            v[4 * g] = f.x; v[4 * g + 1] = f.y; v[4 * g + 2] = f.z; v[4 * g + 3] = f.w;
        }
        // hi of last pair crosses the 64-px row only when idx0%64==48 -> 0
        v[16] = ((idx0 & 63) != 48) ? xp[16] : 0.f;
#pragma unroll
        for (int i = 0; i < 16; ++i)
            tl[i * 256 + t] = (uint_t)f2bf(v[i]) | ((uint_t)f2bf(v[i + 1]) << 16);
        __syncthreads();
        uint_t* op = xpair + (((b << 12) + idx0) << 8);
#pragma unroll
        for (int r = 0; r < 4; ++r) {
            const int l = r * 256 + t;
            const int il = l >> 6, c = (l & 63) << 2;
            *(uint4*)(op + (il << 8) + c) = *(const uint4*)&tl[il * 256 + c];
        }
        return;
    }
    const int wb = bid - XB;
    if (wb < 288) {                                   // w_conv fragment rows
        const int i8 = wb * 256 + t;                  // 0..73727
        const int lane = i8 & 63;
        const int nt = (i8 >> 6) & 15;
        const int kt = i8 >> 10;                      // 0..71
        const int n = nt * 16 + (lane & 15);
        const int k0 = kt * 32 + ((lane >> 4) << 3);
        ushort_t v[8];
#pragma unroll
        for (int j = 0; j < 8; ++j) {
            const int kn = k0 + j;                    // tap-outer: kn = tap*256+cin
            const int cin = kn & 255, tap = kn >> 8;
            v[j] = f2bf(w_conv[n * 2304 + cin * 9 + tap]);
        }
        uint4 o;
        o.x = (uint_t)v[0] | ((uint_t)v[1] << 16);
        o.y = (uint_t)v[2] | ((uint_t)v[3] << 16);
        o.z = (uint_t)v[4] | ((uint_t)v[5] << 16);
        o.w = (uint_t)v[6] | ((uint_t)v[7] << 16);
        *(uint4*)(wfrag + (size_t)i8 * 8) = o;
    } else {                                          // w_off fragment rows (+pad)
        const int i8 = (wb - 288) * 256 + t;          // 0..9215
        const int lane = i8 & 63;
        const int nt = (i8 >> 6) & 1;
        const int kt = i8 >> 7;                       // 0..71
        const int n = nt * 16 + (lane & 15);
        const int k0 = kt * 32 + ((lane >> 4) << 3);
        ushort_t v[8];
#pragma unroll
        for (int j = 0; j < 8; ++j) {
            const int kn = k0 + j;
            const int cin = kn & 255, tap = kn >> 8;
            v[j] = (n < 27) ? f2bf(w_off[n * 2304 + cin * 9 + tap]) : (ushort_t)0;
        }
        uint4 o;
        o.x = (uint_t)v[0] | ((uint_t)v[1] << 16);
        o.y = (uint_t)v[2] | ((uint_t)v[3] << 16);
        o.z = (uint_t)v[4] | ((uint_t)v[5] << 16);
        o.w = (uint_t)v[6] | ((uint_t)v[7] << 16);
        *(uint4*)(wfrag + WOFF_FRAG_OFF + (size_t)i8 * 8) = o;
    }
}

// ---- k_all: block = 32 px x 256 couts, 256 thr = 4 waves, grid 512 ----
template<bool USE_PAIR>
__global__ __launch_bounds__(256, 4) void k_all(
    const float* __restrict__ x,
    const uint_t* __restrict__ xpair,
    const float* __restrict__ b_off,
    const ushort_t* __restrict__ wfrag,
    float* __restrict__ out)
{
    __shared__ short As[2][32 * 264];                // 33,792 B
    __shared__ __align__(16) float4 pwt[9 * 32];     // 4,608 B
    __shared__ __align__(16) int2   pidx[9 * 32];    // 2,304 B  (total 40,704)
    float* om_s = (float*)&As[0][0];                 // 32c x 32px fp32 alias

    const int bid = blockIdx.x;
    const int sid = ((bid & 7) << 6) | (bid >> 3);   // XCD-contiguous bands
    const int m0  = sid << 5;
    const int b   = m0 >> 12;
    const int h   = (m0 >> 6) & 63;
    const int wbase = m0 & 63;                        // 0 or 32
    const int tid  = threadIdx.x;
    const int lane = tid & 63;
    const int wv   = tid >> 6;                        // 0..3
    const int quad = lane >> 4;
    const int px   = tid & 31;                        // staging pixel
    const int slot = tid >> 5;                        // 0..7: 32 cins each

    const float*  xb = x + (b << 20);
    const uint_t* xq = xpair + (b << 20);
    const ushort_t* woffb = wfrag + WOFF_FRAG_OFF;

    // ================= phase 1: offset conv via MFMA =================
    const int m_w = wv & 1, nt_w = wv >> 1;           // 4 waves cover 2m x 2nt
    f32x4 om_acc = {0.f, 0.f, 0.f, 0.f};

    auto stage1 = [&](int tap, int bufi) {
        const int ky = (tap * 11) >> 5, kx = tap - ky * 3;
        const int yy = h + ky - 1;
        const int xx = wbase + px + kx - 1;
        const bool v = ((unsigned)yy < 64u) & ((unsigned)xx < 64u);
        const int idx = v ? (yy << 6) + xx : 0;
        uint_t* dst = (uint_t*)&As[bufi][0] + px * 132 + (slot << 4);
        if (USE_PAIR) {
            const uint_t* p = xq + (idx << 8) + (slot << 5);
#pragma unroll
            for (int hf = 0; hf < 2; ++hf) {
                uint4 r[4];
#pragma unroll
                for (int g = 0; g < 4; ++g) r[g] = *(const uint4*)(p + hf * 16 + g * 4);
                const uint_t* rr = (const uint_t*)r;
                uint_t o[8];
#pragma unroll
                for (int k = 0; k < 8; ++k) {
                    const uint_t l0 = v ? (rr[2 * k] & 0xffffu) : 0u;
                    const uint_t l1 = v ? (rr[2 * k + 1] & 0xffffu) : 0u;
                    o[k] = l0 | (l1 << 16);
                }
                *(uint4*)(dst + hf * 8)     = make_uint4(o[0], o[1], o[2], o[3]);
                *(uint4*)(dst + hf * 8 + 4) = make_uint4(o[4], o[5], o[6], o[7]);
            }
        } else {
#pragma unroll 4
            for (int k = 0; k < 16; ++k) {
                const int cin = (slot << 5) + 2 * k;
                float t0 = xb[(cin << 12) + idx];
                float t1 = xb[((cin + 1) << 12) + idx];
                t0 = v ? t0 : 0.f;  t1 = v ? t1 : 0.f;
                dst[k] = (uint_t)f2bf(t0) | ((uint_t)f2bf(t1) << 16);
            }
        }
    };
    auto mfma1 = [&](int tap) {
        const short* cur = &As[tap & 1][0];
#pragma unroll
        for (int k2 = 0; k2 < 8; ++k2) {
            const int ktg = tap * 8 + k2;
            const short8 a = *(const short8*)&cur[((m_w << 4) + (lane & 15)) * 264 + k2 * 32 + quad * 8];
            const short8 bf = *(const short8*)(woffb + ((ktg * 2 + nt_w) * 64 + lane) * 8);
            om_acc = __builtin_amdgcn_mfma_f32_16x16x32_bf16(a, bf, om_acc, 0, 0, 0);
        }
    };

    stage1(0, 0);
    __syncthreads();
    for (int tap = 0; tap < 9; ++tap) {
        if (tap < 8) stage1(tap + 1, (tap + 1) & 1);
        mfma1(tap);
        __syncthreads();
    }
    {   // C/D: px = m_w*16 + quad*4 + reg; c = nt_w*16 + (lane&15)
        const int c = (nt_w << 4) + (lane & 15);
        *(f32x4*)&om_s[c * 32 + (m_w << 4) + (quad << 2)] = om_acc;
    }
    __syncthreads();

    // ================= phase 2: per-(tap,px) pair-gather params =================
    for (int i2 = tid; i2 < 288; i2 += 256) {
        const int p2 = i2 & 31, tap = i2 >> 5;
        const int ky = (tap * 11) >> 5, kx = tap - ky * 3;
        const float dyv = om_s[(2 * tap) * 32 + p2] + b_off[2 * tap];
        const float dxv = om_s[(2 * tap + 1) * 32 + p2] + b_off[2 * tap + 1];
        const float mo  = om_s[(18 + tap) * 32 + p2] + b_off[18 + tap];
        const float mv  = 1.f / (1.f + expf(-mo));
        const float py  = dyv + (float)(h - 1 + ky);
        const float pxf = dxv + (float)(wbase + p2 - 1 + kx);
        const float y0f = floorf(py), x0f = floorf(pxf);
        const float wy = py - y0f,    wx = pxf - x0f;
        const float vy0 = (y0f >=  0.f && y0f <= 63.f) ? 1.f : 0.f;
        const float vy1 = (y0f >= -1.f && y0f <= 62.f) ? 1.f : 0.f;
        const int ry0 = (int)fminf(fmaxf(y0f, 0.f), 63.f);
        const int ry1 = (int)fminf(fmaxf(y0f + 1.f, 0.f), 63.f);
        const float rw0 = (1.f - wy) * vy0 * mv;
        const float rw1 = wy * vy1 * mv;
        const bool in01 = (x0f >= 0.f && x0f <= 62.f);
        const float wa = in01 ? (1.f - wx) : ((x0f == -1.f) ? wx : 0.f);
        const float wb = in01 ? wx : ((x0f == 63.f) ? (1.f - wx) : 0.f);
        const int bx = (int)fminf(fmaxf(x0f, 0.f), 62.f);
        pwt[i2]  = make_float4(wa, wb, rw0, rw1);
        pidx[i2] = make_int2(ry0 * 64 + bx, ry1 * 64 + bx);
    }
    __syncthreads();

    // ================= phase 3: sampling + main GEMM =================
    f32x4 acc[2][4];
#pragma unroll
    for (int m = 0; m < 2; ++m)
#pragma unroll
        for (int nn = 0; nn < 4; ++nn) acc[m][nn] = f32x4{0.f, 0.f, 0.f, 0.f};

    auto stage3 = [&](int tap, int bufi) {
        const float4 wt = pwt[tap * 32 + px];
        const int2   ii = pidx[tap * 32 + px];
        uint_t* dst = (uint_t*)&As[bufi][0] + px * 132 + (slot << 4);
        if (USE_PAIR) {
            const uint_t* p0 = xq + (ii.x << 8) + (slot << 5);
            const uint_t* p1 = xq + (ii.y << 8) + (slot << 5);
#pragma unroll
            for (int hf = 0; hf < 2; ++hf) {
                uint4 r0[4], r1[4];
#pragma unroll
                for (int g = 0; g < 4; ++g) {
                    r0[g] = *(const uint4*)(p0 + hf * 16 + g * 4);
                    r1[g] = *(const uint4*)(p1 + hf * 16 + g * 4);
                }
                const uint_t* a0 = (const uint_t*)r0;
                const uint_t* a1 = (const uint_t*)r1;
                uint_t o[8];
#pragma unroll
                for (int k = 0; k < 8; ++k) {
                    ushort_t s[2];
#pragma unroll
                    for (int u = 0; u < 2; ++u) {
                        const int c = 2 * k + u;
                        const float v = (bflo(a0[c]) * wt.x + bfhi(a0[c]) * wt.y) * wt.z
                                      + (bflo(a1[c]) * wt.x + bfhi(a1[c]) * wt.y) * wt.w;
                        s[u] = f2bf(v);
                    }
                    o[k] = (uint_t)s[0] | ((uint_t)s[1] << 16);
                }
                *(uint4*)(dst + hf * 8)     = make_uint4(o[0], o[1], o[2], o[3]);
                *(uint4*)(dst + hf * 8 + 4) = make_uint4(o[4], o[5], o[6], o[7]);
            }
        } else {
#pragma unroll 4
            for (int k = 0; k < 16; ++k) {
                ushort_t s[2];
#pragma unroll
                for (int u = 0; u < 2; ++u) {
                    const int cin = (slot << 5) + 2 * k + u;
                    const pairf pa = *(const pairf*)(xb + (cin << 12) + ii.x);
                    const pairf pb = *(const pairf*)(xb + (cin << 12) + ii.y);
                    const float v = (pa.x * wt.x + pa.y * wt.y) * wt.z
                                  + (pb.x * wt.x + pb.y * wt.y) * wt.w;
                    s[u] = f2bf(v);
                }
                dst[k] = (uint_t)s[0] | ((uint_t)s[1] << 16);
            }
        }
    };
    auto mfma3 = [&](int tap) {
        const short* cur = &As[tap & 1][0];
#pragma unroll
        for (int k2 = 0; k2 < 8; ++k2) {
            const int ktg = tap * 8 + k2;
            short8 a0 = *(const short8*)&cur[(lane & 15) * 264 + k2 * 32 + quad * 8];
            short8 a1 = *(const short8*)&cur[((lane & 15) + 16) * 264 + k2 * 32 + quad * 8];
#pragma unroll
            for (int nn = 0; nn < 4; ++nn) {
                const short8 bf = *(const short8*)(wfrag + ((ktg * 16 + (wv << 2) + nn) * 64 + lane) * 8);
                acc[0][nn] = __builtin_amdgcn_mfma_f32_16x16x32_bf16(a0, bf, acc[0][nn], 0, 0, 0);
                acc[1][nn] = __builtin_amdgcn_mfma_f32_16x16x32_bf16(a1, bf, acc[1][nn], 0, 0, 0);
            }
        }
    };

    stage3(0, 0);
    __syncthreads();
    for (int tap = 0; tap < 9; ++tap) {
        if (tap < 8) stage3(tap + 1, (tap + 1) & 1);
        mfma3(tap);
        __syncthreads();
    }

    // epilogue: w = wbase + m*16 + quad*4 + reg; cout n = wv*64 + nn*16 + (lane&15)
#pragma unroll
    for (int m = 0; m < 2; ++m) {
        const int w = wbase + (m << 4) + (quad << 2);
#pragma unroll
        for (int nn = 0; nn < 4; ++nn) {
            const int n = (wv << 6) + (nn << 4) + (lane & 15);
            float* op = out + (((size_t)((b << 8) + n)) << 12) + (h << 6) + w;
            *(f32x4*)op = acc[m][nn];
        }
    }
}

extern "C" void kernel_launch(void* const* d_in, const int* in_sizes, int n_in,
                              void* d_out, int out_size, void* d_ws, size_t ws_size,
                              hipStream_t stream) {
    const float* x      = (const float*)d_in[0];
    const float* w_off  = (const float*)d_in[1];
    const float* b_off  = (const float*)d_in[2];
    const float* w_conv = (const float*)d_in[3];
    float* out = (float*)d_out;

    const size_t need = 4194304ull * 4 + 663552ull * 2;   // 18,104,320 B
    const bool use_pair = (ws_size >= need);

    uint_t*   xpair = (uint_t*)d_ws;
    ushort_t* wfrag = use_pair ? (ushort_t*)((char*)d_ws + 4194304ull * 4)
                               : (ushort_t*)d_ws;
    const int XB = use_pair ? 1024 : 0;

    hipLaunchKernelGGL(k_pre, dim3(XB + 324), dim3(256), 0, stream,
                       x, w_conv, w_off, wfrag, xpair, XB);
    if (use_pair)
        hipLaunchKernelGGL((k_all<true>), dim3(512), dim3(256), 0, stream,
                           x, xpair, b_off, wfrag, out);
    else
        hipLaunchKernelGGL((k_all<false>), dim3(512), dim3(256), 0, stream,
                           x, xpair, b_off, wfrag, out);
}